// Round 11
// baseline (891.494 us; speedup 1.0000x reference)
//
#include <hip/hip_runtime.h>
#include <hip/hip_bf16.h>

#define D 128
#define DFF 512
#define NLAYER 4
#define NCLS 10
#define NN 131072
#define NLEAF 65536
#define ETOT 655360
#define NREAD 4096

typedef unsigned short u16;
typedef unsigned int u32;
typedef __attribute__((ext_vector_type(8))) short bf16x8;
typedef __attribute__((ext_vector_type(16))) float f32x16;
typedef u32 u32x4 __attribute__((ext_vector_type(4)));

#define MFMA32(a,b,c) __builtin_amdgcn_mfma_f32_32x32x16_bf16(a,b,c,0,0,0)

__device__ __forceinline__ float b2f(u16 u){ u32 x = ((u32)u)<<16; return __builtin_bit_cast(float, x); }
__device__ __forceinline__ u16 f2b(float f){ u32 i = __builtin_bit_cast(u32, f); u32 r = (i + 0x7FFFu + ((i>>16)&1u))>>16; return (u16)r; }
__device__ __forceinline__ float blo(u32 u){ return __builtin_bit_cast(float, u<<16); }
__device__ __forceinline__ float bhi(u32 u){ return __builtin_bit_cast(float, u & 0xffff0000u); }

__device__ __forceinline__ float wredsum(float v){
  v += __shfl_xor(v,32); v += __shfl_xor(v,16); v += __shfl_xor(v,8);
  v += __shfl_xor(v,4);  v += __shfl_xor(v,2);  v += __shfl_xor(v,1);
  return v;
}
__device__ __forceinline__ float rsum32(float v){
  v += __shfl_xor(v,1); v += __shfl_xor(v,2); v += __shfl_xor(v,4);
  v += __shfl_xor(v,8); v += __shfl_xor(v,16);
  return v;
}

// swizzled LDS read: byte = row*256 + (bytecol ^ ((row&7)<<4))
__device__ __forceinline__ bf16x8 ldfrag(const u16* buf, int row, int kbyte){
  return *(const bf16x8*)((const char*)buf + row*256 + ((u32)kbyte ^ (u32)((row&7)<<4)));
}

// stage 128x128 bf16 tile into LDS via global_load_lds (linear dest, pre-swizzled src)
// NW = waves per block; wave wv_ stages rows [wv_*(128/NW), ...)
template<int NW>
__device__ __forceinline__ void stage_B(const u16* __restrict__ src, int strideElems, int colOff,
                                        u16* BsBase, int wv_, int lane){
  const int RPW = 128/NW;            // rows per wave
  int rb = wv_*RPW + (lane>>4);
  int slotbase = lane & 15;
  #pragma unroll
  for(int it=0; it<RPW/4; it++){
    int r = rb + it*4;
    int slot = slotbase ^ (r&7);
    __builtin_amdgcn_global_load_lds(
      (const __attribute__((address_space(1))) unsigned*)(src + (size_t)r*strideElems + colOff + slot*8),
      (__attribute__((address_space(3))) unsigned*)((char*)BsBase + wv_*RPW*256 + it*1024),
      16, 0, 0);
  }
}

// MFMA over K=128 with A fragments in registers, B in swizzled LDS
__device__ __forceinline__ void mfma_regA(const bf16x8 af[8], const u16* Bs,
                                          int l31, int lkh, f32x16 acc[4]){
  #pragma unroll
  for(int kk=0;kk<8;kk++){
    #pragma unroll
    for(int c=0;c<4;c++){
      bf16x8 bf = ldfrag(Bs, c*32 + l31, kk*32 + lkh);
      acc[c] = MFMA32(af[kk], bf, acc[c]);
    }
  }
}

// residual(bf16) + LayerNorm epilogue -> hb
__device__ __forceinline__ void ln_epilogue(f32x16 acc[4], size_t r0, int wrow0, int l31, int h5,
    const float* g, const float* b, u16* hb){
  float gc[4], bc[4];
  #pragma unroll
  for(int c=0;c<4;c++){ int col = c*32 + l31; gc[c]=g[col]; bc[c]=b[col]; }
  #pragma unroll
  for(int r=0;r<16;r++){
    int rowl = wrow0 + (r&3) + 8*(r>>2) + 4*h5;
    size_t base = (r0 + rowl)*(size_t)D;
    float v[4];
    #pragma unroll
    for(int c=0;c<4;c++) v[c] = acc[c][r] + b2f(hb[base + c*32 + l31]);
    float s = rsum32(v[0]+v[1]+v[2]+v[3]);
    float mean = s * (1.0f/128.0f);
    float dd[4]; float q = 0.f;
    #pragma unroll
    for(int c=0;c<4;c++){ dd[c]=v[c]-mean; q += dd[c]*dd[c]; }
    q = rsum32(q);
    float rs = rsqrtf(q*(1.0f/128.0f) + 1e-5f);
    #pragma unroll
    for(int c=0;c<4;c++){
      float o = dd[c]*rs*gc[c] + bc[c];
      hb[base + c*32 + l31] = f2b(o);
    }
  }
}

// ---------------- h0 -> hb (bf16) ----------------
__global__ __launch_bounds__(256) void k_hinit(const float* __restrict__ h0, u16* __restrict__ hb){
  int i = blockIdx.x*256 + threadIdx.x;
  float4 v = ((const float4*)h0)[i];
  ushort4 p; p.x=f2b(v.x); p.y=f2b(v.y); p.z=f2b(v.z); p.w=f2b(v.w);
  ((ushort4*)hb)[i] = p;
}

// ---------------- leaf embedding + LN ----------------
__global__ __launch_bounds__(256) void k_embed(const int* __restrict__ x, const int* __restrict__ pos,
    const int* __restrict__ leaf, const float* __restrict__ emb,
    const float* __restrict__ g, const float* __restrict__ b, u16* __restrict__ hb){
  int row = blockIdx.x*4 + (threadIdx.x>>6);
  int lane = threadIdx.x & 63;
  int tok = x[row]; float p = (float)pos[row];
  float v[2];
  #pragma unroll
  for(int j=0;j<2;j++){
    int d = lane + 64*j;
    float freq = expf(-0.07195578515529633f * (float)(d & ~1));
    float ang = p * freq;
    float pe = (d&1) ? cosf(ang) : sinf(ang);
    v[j] = emb[(size_t)tok*D + d] * 11.313708498984761f + pe;
  }
  float mean = wredsum(v[0]+v[1]) * (1.0f/128.0f);
  float d0 = v[0]-mean, d1 = v[1]-mean;
  float var = wredsum(d0*d0 + d1*d1) * (1.0f/128.0f);
  float rs = rsqrtf(var + 1e-5f);
  size_t orow = (size_t)leaf[row];
  hb[orow*D + lane]      = f2b(d0*rs*g[lane]    + b[lane]);
  hb[orow*D + lane + 64] = f2b(d1*rs*g[lane+64] + b[lane+64]);
}

// ---------------- weight transpose + bf16 convert ----------------
__global__ __launch_bounds__(256) void k_wconv(const float* __restrict__ Wq, const float* __restrict__ Wk,
    const float* __restrict__ Wv, const float* __restrict__ Wo,
    const float* __restrict__ W1, const float* __restrict__ W2,
    u16* __restrict__ wqt, u16* __restrict__ wkt, u16* __restrict__ wvt, u16* __restrict__ wot,
    u16* __restrict__ w1t, u16* __restrict__ w2t){
  int e = blockIdx.x*256 + threadIdx.x;     // NLAYER*196608 total
  int l = e / 196608, r = e % 196608;
  if(r < 65536){
    int w = r >> 14, i = r & 16383;
    int n = i >> 7, k = i & 127;
    const float* src = (w==0)?Wq:(w==1)?Wk:(w==2)?Wv:Wo;
    u16* dst = (w==0)?wqt:(w==1)?wkt:(w==2)?wvt:wot;
    dst[l*16384 + n*128 + k] = f2b(src[l*16384 + k*128 + n]);
  } else if(r < 131072){
    int i = r - 65536; int n = i >> 7, k = i & 127;      // n in 0..511
    w1t[l*65536 + n*128 + k] = f2b(W1[l*65536 + k*512 + n]);
  } else {
    int i = r - 131072; int n = i >> 9, f = i & 511;     // n in 0..127
    w2t[l*65536 + n*512 + f] = f2b(W2[l*65536 + f*128 + n]);
  }
}

// ---------------- CSR build ----------------
__global__ __launch_bounds__(256) void k_count(const int* __restrict__ dst, int* __restrict__ cnt){
  int e = blockIdx.x*256 + threadIdx.x;
  atomicAdd(&cnt[dst[e]], 1);
}
__global__ __launch_bounds__(256) void k_scan1(const int* __restrict__ cnt, int* __restrict__ part,
                                               int* __restrict__ bsum){
  __shared__ int s[256];
  int tid = threadIdx.x; int i = blockIdx.x*256 + tid;
  int v = cnt[i]; s[tid]=v; __syncthreads();
  for(int off=1; off<256; off<<=1){
    int t=(tid>=off)? s[tid-off]:0; __syncthreads();
    s[tid]+=t; __syncthreads();
  }
  part[i] = s[tid]-v;
  if(tid==255) bsum[blockIdx.x] = s[255];
}
__global__ __launch_bounds__(512) void k_scan2(int* __restrict__ bsum){
  __shared__ int s[512];
  int tid = threadIdx.x;
  int v = bsum[tid]; s[tid] = v; __syncthreads();
  for(int off=1; off<512; off<<=1){
    int t = (tid>=off)? s[tid-off]:0; __syncthreads();
    s[tid] += t; __syncthreads();
  }
  bsum[tid] = s[tid] - v;
}
__global__ __launch_bounds__(256) void k_scan3(const int* __restrict__ part, const int* __restrict__ bsum,
                                               int* __restrict__ indptr, int* __restrict__ cursor){
  int i = blockIdx.x*256 + threadIdx.x;
  int v = part[i] + bsum[i>>8];
  indptr[i] = v; cursor[i] = v;
  if(i==0) indptr[NN] = ETOT;
}
__global__ __launch_bounds__(256) void k_scatter(const int* __restrict__ src, const int* __restrict__ dst,
    int* __restrict__ cursor, int* __restrict__ esrc){
  int e = blockIdx.x*256 + threadIdx.x;
  int p = atomicAdd(&cursor[dst[e]], 1);
  esrc[p] = src[e];
}

// ------- QKV GEMM: 512 threads, 256 rows/block; one block does q,k,v ---------------
__global__ __launch_bounds__(512,4) void k_qkv(const u16* __restrict__ hb,
    const u16* __restrict__ wqt, const u16* __restrict__ wkt, const u16* __restrict__ wvt,
    const float* __restrict__ bq, const float* __restrict__ bk, const float* __restrict__ bv,
    u16* __restrict__ qb, u16* __restrict__ kb, u16* __restrict__ vb){
  __shared__ u16 Bs[128*128];
  int tid = threadIdx.x;
  int lane = tid & 63, wv_ = tid >> 6;          // 8 waves
  int l31 = lane & 31, h5 = lane >> 5, lkh = h5*16;
  int wrow0 = wv_*32;                            // 0..224
  size_t r0 = (size_t)blockIdx.x * 256;

  stage_B<8>(wqt, D, 0, Bs, wv_, lane);
  bf16x8 af[8];
  const u16* arow = hb + (r0 + wrow0 + l31)*(size_t)D + h5*8;
  #pragma unroll
  for(int kk=0;kk<8;kk++) af[kk] = *(const bf16x8*)(arow + kk*16);

  const u16* wt[3]    = {wqt,wkt,wvt};
  const float* bias[3] = {bq,bk,bv};
  u16* outp[3] = {qb,kb,vb};
  #pragma unroll
  for(int w=0; w<3; w++){
    if(w){
      __syncthreads();                 // prior mfma done reading Bs
      stage_B<8>(wt[w], D, 0, Bs, wv_, lane);
    }
    f32x16 acc[4];
    #pragma unroll
    for(int c=0;c<4;c++){
      float bb = bias[w][c*32+l31];
      #pragma unroll
      for(int i=0;i<16;i++) acc[c][i] = bb;
    }
    __syncthreads();                   // staging complete
    mfma_regA(af, Bs, l31, lkh, acc);
    u16* op = outp[w];
    #pragma unroll
    for(int c=0;c<4;c++){
      int col = c*32 + l31;
      #pragma unroll
      for(int r=0;r<16;r++){
        int row = wrow0 + (r&3) + 8*(r>>2) + 4*h5;
        op[(r0+row)*(size_t)D + col] = f2b(acc[c][r]);
      }
    }
  }
}

// ------- attention: one wave/node; peeled first batch; MSB-first reduce-scatter ------
__global__ __launch_bounds__(256,6) void k_attn(const u16* qb, const u16* __restrict__ kb,
    const u16* __restrict__ vb, const int* __restrict__ indptr, const int* __restrict__ esrc,
    u16* aggb){
  int node = blockIdx.x*4 + (threadIdx.x>>6);
  int lane = threadIdx.x & 63;
  int hd = lane >> 3, eslot = lane & 7;
  int beg = indptr[node], end = indptr[node+1];
  float qr[16];
  {
    const uint4* qp = (const uint4*)(qb + (size_t)node*D + hd*16);
    uint4 a = qp[0], b = qp[1];
    u32 w[8] = {a.x,a.y,a.z,a.w,b.x,b.y,b.z,b.w};
    #pragma unroll
    for(int i=0;i<8;i++){ qr[2*i] = blo(w[i]); qr[2*i+1] = bhi(w[i]); }
  }
  float m = -3.0e38f, den = 0.f;
  float acc[16];
  #pragma unroll
  for(int i=0;i<16;i++) acc[i] = 0.f;

  // ---- peeled first batch: m=p, den=1, acc=v exactly (exp(0)=1) ----
  {
    int e = beg + eslot;
    if(e < end){
      int s = esrc[e];
      const uint4* kp = (const uint4*)(kb + (size_t)s*D + hd*16);
      uint4 k0 = kp[0], k1 = kp[1];
      const uint4* vp = (const uint4*)(vb + (size_t)s*D + hd*16);
      uint4 v0 = vp[0], v1 = vp[1];
      u32 kw[8] = {k0.x,k0.y,k0.z,k0.w,k1.x,k1.y,k1.z,k1.w};
      float p = 0.f, p2 = 0.f;
      #pragma unroll
      for(int i=0;i<8;i++){ p = fmaf(blo(kw[i]), qr[2*i], p); p2 = fmaf(bhi(kw[i]), qr[2*i+1], p2); }
      m = (p + p2)*0.25f;
      den = 1.f;
      u32 vw[8] = {v0.x,v0.y,v0.z,v0.w,v1.x,v1.y,v1.z,v1.w};
      #pragma unroll
      for(int i=0;i<8;i++){ acc[2*i] = blo(vw[i]); acc[2*i+1] = bhi(vw[i]); }
    }
  }
  // ---- remaining batches: full online-softmax update ----
  for(int e0=beg+8; e0<end; e0+=8){
    int e = e0 + eslot;
    if(e < end){
      int s = esrc[e];
      const uint4* kp = (const uint4*)(kb + (size_t)s*D + hd*16);
      uint4 k0 = kp[0], k1 = kp[1];
      const uint4* vp = (const uint4*)(vb + (size_t)s*D + hd*16);
      uint4 v0 = vp[0], v1 = vp[1];
      u32 kw[8] = {k0.x,k0.y,k0.z,k0.w,k1.x,k1.y,k1.z,k1.w};
      float p = 0.f, p2 = 0.f;
      #pragma unroll
      for(int i=0;i<8;i++){ p = fmaf(blo(kw[i]), qr[2*i], p); p2 = fmaf(bhi(kw[i]), qr[2*i+1], p2); }
      p = (p + p2)*0.25f;                       // 1/sqrt(DK)
      float nm = fmaxf(m, p);
      float fs = __expf(m - nm);
      float w  = __expf(p - nm);
      den = den*fs + w;
      u32 vw[8] = {v0.x,v0.y,v0.z,v0.w,v1.x,v1.y,v1.z,v1.w};
      #pragma unroll
      for(int i=0;i<8;i++){
        acc[2*i]   = fmaf(acc[2*i],   fs, w*blo(vw[i]));
        acc[2*i+1] = fmaf(acc[2*i+1], fs, w*bhi(vw[i]));
      }
      m = nm;
    }
  }
  // merge (m, den) across 8 slots
  float mo = m;
  #pragma unroll
  for(int s=1; s<8; s<<=1){
    float m2 = __shfl_xor(m, s); float d2 = __shfl_xor(den, s);
    float nm = fmaxf(m, m2);
    den = den*__expf(m-nm) + d2*__expf(m2-nm);
    m = nm;
  }
  // rescale local partials, then MSB-first reduce-scatter (lane ends owning dims 2*eslot)
  float sc = __expf(mo - m);
  #pragma unroll
  for(int i=0;i<16;i++) acc[i] *= sc;
  #pragma unroll
  for(int lvl=0; lvl<3; lvl++){
    const int half = 8 >> lvl;          // 8,4,2
    const int msk = 4 >> lvl;           // 4,2,1  (MSB first!)
    bool hi = (eslot & msk) != 0;
    #pragma unroll
    for(int i=0;i<half;i++){
      float a = acc[i], b = acc[i+half];
      acc[i]      = hi ? b : a;
      acc[i+half] = hi ? a : b;
    }
    #pragma unroll
    for(int i=0;i<half;i++) acc[i] += __shfl_xor(acc[i+half], msk);
  }
  // lane owns dims (2*eslot, 2*eslot+1): store byte offset = lane*4 -> fully coalesced
  float rin = 1.0f/den;
  u32 pk = (u32)f2b(acc[0]*rin) | ((u32)f2b(acc[1]*rin)<<16);
  *(u32*)(aggb + (size_t)node*D + hd*16 + eslot*2) = pk;
}

// ---------------- O-proj + residual + LN1: 512 threads, 256 rows/block ---------------
__global__ __launch_bounds__(512,4) void k_owo(const u16* __restrict__ aggb, const u16* __restrict__ wot,
    const float* __restrict__ bo, const float* __restrict__ g1, const float* __restrict__ b1,
    u16* hb){
  __shared__ u16 Bs[128*128];
  int tid = threadIdx.x;
  int lane = tid & 63, wv_ = tid >> 6;          // 8 waves
  int l31 = lane & 31, h5 = lane >> 5, lkh = h5*16;
  int wrow0 = wv_*32;
  size_t r0 = (size_t)blockIdx.x * 256;
  stage_B<8>(wot, D, 0, Bs, wv_, lane);
  bf16x8 af[8];
  const u16* arow = aggb + (r0 + wrow0 + l31)*(size_t)D + h5*8;
  #pragma unroll
  for(int kk=0;kk<8;kk++) af[kk] = *(const bf16x8*)(arow + kk*16);
  f32x16 acc[4];
  #pragma unroll
  for(int c=0;c<4;c++){
    float bb = bo[c*32+l31];
    #pragma unroll
    for(int i=0;i<16;i++) acc[c][i] = bb;
  }
  __syncthreads();
  mfma_regA(af, Bs, l31, lkh, acc);
  ln_epilogue(acc, r0, wrow0, l31, h5, g1, b1, hb);
}

// ---------------- FFN: in-register transpose between the two GEMMs (unchanged) -------
__global__ __launch_bounds__(256,2) void k_ffn(const u16* __restrict__ w1t, const u16* __restrict__ w2t,
    const float* __restrict__ b1, const float* __restrict__ b2,
    const float* __restrict__ g2, const float* __restrict__ bb2,
    u16* hb){
  __shared__ u16 B1s[128*128];
  __shared__ u16 B2s[128*128];
  int tid = threadIdx.x;
  int lane = tid & 63, wv_ = tid >> 6;
  int l31 = lane & 31, h5 = lane >> 5, lkh = h5*16;
  int wrow0 = wv_*32;
  size_t r0 = (size_t)blockIdx.x * 128;
  bf16x8 af[8];
  const u16* arow = hb + (r0 + wrow0 + l31)*(size_t)D + h5*8;
  #pragma unroll
  for(int kk=0;kk<8;kk++) af[kk] = *(const bf16x8*)(arow + kk*16);
  f32x16 out[4];
  #pragma unroll
  for(int c=0;c<4;c++){
    float bb = b2[c*32+l31];
    #pragma unroll
    for(int i=0;i<16;i++) out[c][i] = bb;
  }
  for(int ch=0; ch<4; ch++){
    if(ch) __syncthreads();
    stage_B<4>(w1t + ch*128*D, D, 0, B1s, wv_, lane);
    stage_B<4>(w2t, DFF, ch*128, B2s, wv_, lane);
    __syncthreads();
    // stage1: acc2[c] = (W1 chunk)(A: rows f) x (af)(B: cols = wave's 32 nodes) = T^T
    f32x16 acc2[4];
    #pragma unroll
    for(int c=0;c<4;c++){
      #pragma unroll
      for(int r=0;r<16;r++){
        int foff = (r&3) + 8*(r>>2) + 4*h5;
        acc2[c][r] = b1[ch*128 + c*32 + foff];
      }
    }
    #pragma unroll
    for(int kk=0;kk<8;kk++){
      #pragma unroll
      for(int c=0;c<4;c++){
        bf16x8 w1f = ldfrag(B1s, c*32 + l31, kk*32 + lkh);
        acc2[c] = MFMA32(w1f, af[kk], acc2[c]);
      }
    }
    // relu + pack bf16 + h5 half-exchange -> A-fragments for stage2
    bf16x8 af2[8];
    bool hb5 = (h5 != 0);
    #pragma unroll
    for(int c=0;c<4;c++){
      u32 pk[8];
      #pragma unroll
      for(int t=0;t<8;t++){
        float lo  = fmaxf(acc2[c][2*t],   0.f);
        float hi2 = fmaxf(acc2[c][2*t+1], 0.f);
        u32 r_;
        asm("v_cvt_pk_bf16_f32 %0, %1, %2" : "=v"(r_) : "v"(lo), "v"(hi2));
        pk[t] = r_;
      }
      // h5=0 holds f-offsets {0,2,8,10,16,18,24,26}; h5=1 holds {4,6,12,14,20,22,28,30}
      u32 s0 = hb5 ? pk[0] : pk[2];
      u32 s1 = hb5 ? pk[1] : pk[3];
      u32 s2 = hb5 ? pk[4] : pk[6];
      u32 s3 = hb5 ? pk[5] : pk[7];
      u32 g0 = (u32)__shfl_xor((int)s0, 32);
      u32 g1 = (u32)__shfl_xor((int)s1, 32);
      u32 g2_ = (u32)__shfl_xor((int)s2, 32);
      u32 g3 = (u32)__shfl_xor((int)s3, 32);
      u32x4 A0 = { hb5 ? g0 : pk[0], hb5 ? g1 : pk[1], hb5 ? pk[2] : g0, hb5 ? pk[3] : g1 };
      u32x4 A1 = { hb5 ? g2_ : pk[4], hb5 ? g3 : pk[5], hb5 ? pk[6] : g2_, hb5 ? pk[7] : g3 };
      af2[2*c]   = __builtin_bit_cast(bf16x8, A0);
      af2[2*c+1] = __builtin_bit_cast(bf16x8, A1);
    }
    // stage2: out += T(A: rows = wave's nodes) x (W2 chunk)(B: cols n)
    #pragma unroll
    for(int kk=0;kk<8;kk++){
      #pragma unroll
      for(int c=0;c<4;c++){
        bf16x8 w2f = ldfrag(B2s, c*32 + l31, kk*32 + lkh);
        out[c] = MFMA32(af2[kk], w2f, out[c]);
      }
    }
  }
  ln_epilogue(out, r0, wrow0, l31, h5, g2, bb2, hb);
}

// ---------------- readout ----------------
__global__ __launch_bounds__(64) void k_readout(const u16* __restrict__ hb, const int* __restrict__ rid,
    const float* __restrict__ gw, const float* __restrict__ gb, float* __restrict__ out){
  int r = blockIdx.x; int lane = threadIdx.x;
  size_t node = (size_t)rid[r];
  float h0v = b2f(hb[node*D + lane]), h1v = b2f(hb[node*D + 64 + lane]);
  float lg[NCLS];
  #pragma unroll
  for(int c=0;c<NCLS;c++){
    float p = h0v*gw[lane*NCLS + c] + h1v*gw[(lane+64)*NCLS + c];
    lg[c] = wredsum(p) + gb[c];
  }
  float mx = lg[0];
  #pragma unroll
  for(int c=1;c<NCLS;c++) mx = fmaxf(mx, lg[c]);
  float se = 0.f;
  #pragma unroll
  for(int c=0;c<NCLS;c++) se += expf(lg[c]-mx);
  float lse = mx + logf(se);
  if(lane < NCLS) out[(size_t)r*NCLS + lane] = lg[lane] - lse;
}

extern "C" void kernel_launch(void* const* d_in, const int* in_sizes, int n_in,
                              void* d_out, int out_size, void* d_ws, size_t ws_size,
                              hipStream_t stream) {
  const int* x    = (const int*)d_in[0];
  const int* pos  = (const int*)d_in[1];
  const int* leaf = (const int*)d_in[2];
  const int* src  = (const int*)d_in[3];
  const int* dst  = (const int*)d_in[4];
  const int* rid  = (const int*)d_in[5];
  const float* h0 = (const float*)d_in[6];
  const float* emb= (const float*)d_in[7];
  const float* eng= (const float*)d_in[8];
  const float* enb= (const float*)d_in[9];
  const float* Wq = (const float*)d_in[10];
  const float* bq = (const float*)d_in[11];
  const float* Wk = (const float*)d_in[12];
  const float* bk = (const float*)d_in[13];
  const float* Wv = (const float*)d_in[14];
  const float* bv = (const float*)d_in[15];
  const float* Wo = (const float*)d_in[16];
  const float* bo = (const float*)d_in[17];
  const float* l1g= (const float*)d_in[18];
  const float* l1b= (const float*)d_in[19];
  const float* W1 = (const float*)d_in[20];
  const float* b1 = (const float*)d_in[21];
  const float* W2 = (const float*)d_in[22];
  const float* b2 = (const float*)d_in[23];
  const float* l2g= (const float*)d_in[24];
  const float* l2b= (const float*)d_in[25];
  const float* gw = (const float*)d_in[26];
  const float* gb = (const float*)d_in[27];
  float* out = (float*)d_out;

  char* ws = (char*)d_ws;
  u16* hb     = (u16*)(ws);                          // 33,554,432
  u16* qb     = (u16*)(ws + 33554432);               // 33,554,432 (agg aliases)
  u16* kb     = (u16*)(ws + 67108864);               // 33,554,432
  u16* vb     = (u16*)(ws + 100663296);              // 33,554,432
  u16* wqt    = (u16*)(ws + 134217728);              // 131,072
  u16* wkt    = (u16*)(ws + 134348800);
  u16* wvt    = (u16*)(ws + 134479872);
  u16* wot    = (u16*)(ws + 134610944);
  u16* w1t    = (u16*)(ws + 134742016);              // 524,288
  u16* w2t    = (u16*)(ws + 135266304);              // 524,288
  int* indptr = (int*)(ws + 135790592);              // 524,544
  int* cursor = (int*)(ws + 136315136);              // 524,288
  int* part   = (int*)(ws + 136839424);              // 524,288
  int* bsum   = (int*)(ws + 137363712);              // 2,048
  int* esrc   = (int*)(ws + 137365760);              // 2,621,440  -> ~140 MB total

  k_hinit<<<NN*D/4/256, 256, 0, stream>>>(h0, hb);
  k_embed<<<NLEAF/4, 256, 0, stream>>>(x, pos, leaf, emb, eng, enb, hb);
  k_wconv<<<NLAYER*196608/256, 256, 0, stream>>>(Wq,Wk,Wv,Wo,W1,W2, wqt,wkt,wvt,wot,w1t,w2t);

  hipMemsetAsync(cursor, 0, NN*sizeof(int), stream);
  k_count  <<<ETOT/256, 256, 0, stream>>>(dst, cursor);
  k_scan1  <<<NN/256, 256, 0, stream>>>(cursor, part, bsum);
  k_scan2  <<<1, 512, 0, stream>>>(bsum);
  k_scan3  <<<NN/256, 256, 0, stream>>>(part, bsum, indptr, cursor);
  k_scatter<<<ETOT/256, 256, 0, stream>>>(src, dst, cursor, esrc);

  for(int l=0; l<NLAYER; l++){
    k_qkv<<<NN/256, 512, 0, stream>>>(hb, wqt + l*16384, wkt + l*16384, wvt + l*16384,
                                      bq + l*D, bk + l*D, bv + l*D, qb, kb, vb);
    k_attn<<<NN/4, 256, 0, stream>>>(qb, kb, vb, indptr, esrc, qb);
    k_owo<<<NN/256, 512, 0, stream>>>(qb, wot + l*16384, bo + l*D,
                                      l1g + l*D, l1b + l*D, hb);
    k_ffn<<<NN/128, 256, 0, stream>>>(w1t + l*65536, w2t + l*65536,
                                      b1 + l*DFF, b2 + l*D, l2g + l*D, l2b + l*D, hb);
  }
  k_readout<<<NREAD, 64, 0, stream>>>(hb, rid, gw, gb, out);
}

// Round 12
// 791.026 us; speedup vs baseline: 1.1270x; 1.1270x over previous
//
#include <hip/hip_runtime.h>
#include <hip/hip_bf16.h>

#define D 128
#define DFF 512
#define NLAYER 4
#define NCLS 10
#define NN 131072
#define NLEAF 65536
#define ETOT 655360
#define NREAD 4096

typedef unsigned short u16;
typedef unsigned int u32;
typedef __attribute__((ext_vector_type(8))) short bf16x8;
typedef __attribute__((ext_vector_type(16))) float f32x16;
typedef u32 u32x4 __attribute__((ext_vector_type(4)));

#define MFMA32(a,b,c) __builtin_amdgcn_mfma_f32_32x32x16_bf16(a,b,c,0,0,0)

__device__ __forceinline__ float b2f(u16 u){ u32 x = ((u32)u)<<16; return __builtin_bit_cast(float, x); }
__device__ __forceinline__ u16 f2b(float f){ u32 i = __builtin_bit_cast(u32, f); u32 r = (i + 0x7FFFu + ((i>>16)&1u))>>16; return (u16)r; }
__device__ __forceinline__ float blo(u32 u){ return __builtin_bit_cast(float, u<<16); }
__device__ __forceinline__ float bhi(u32 u){ return __builtin_bit_cast(float, u & 0xffff0000u); }

__device__ __forceinline__ float wredsum(float v){
  v += __shfl_xor(v,32); v += __shfl_xor(v,16); v += __shfl_xor(v,8);
  v += __shfl_xor(v,4);  v += __shfl_xor(v,2);  v += __shfl_xor(v,1);
  return v;
}
__device__ __forceinline__ float rsum32(float v){
  v += __shfl_xor(v,1); v += __shfl_xor(v,2); v += __shfl_xor(v,4);
  v += __shfl_xor(v,8); v += __shfl_xor(v,16);
  return v;
}

// swizzled LDS read: byte = row*256 + (bytecol ^ ((row&7)<<4))
__device__ __forceinline__ bf16x8 ldfrag(const u16* buf, int row, int kbyte){
  return *(const bf16x8*)((const char*)buf + row*256 + ((u32)kbyte ^ (u32)((row&7)<<4)));
}

// stage 128x128 bf16 tile into LDS via global_load_lds (linear dest, pre-swizzled src)
__device__ __forceinline__ void stage_B(const u16* __restrict__ src, int strideElems, int colOff,
                                        u16* BsBase, int wv_, int lane){
  int rb = wv_*32 + (lane>>4);
  int slotbase = lane & 15;
  #pragma unroll
  for(int it=0; it<8; it++){
    int r = rb + it*4;
    int slot = slotbase ^ (r&7);
    __builtin_amdgcn_global_load_lds(
      (const __attribute__((address_space(1))) unsigned*)(src + (size_t)r*strideElems + colOff + slot*8),
      (__attribute__((address_space(3))) unsigned*)((char*)BsBase + wv_*8192 + it*1024),
      16, 0, 0);
  }
}

// MFMA over K=128 with A fragments in registers, B in swizzled LDS
__device__ __forceinline__ void mfma_regA(const bf16x8 af[8], const u16* Bs,
                                          int l31, int lkh, f32x16 acc[4]){
  #pragma unroll
  for(int kk=0;kk<8;kk++){
    #pragma unroll
    for(int c=0;c<4;c++){
      bf16x8 bf = ldfrag(Bs, c*32 + l31, kk*32 + lkh);
      acc[c] = MFMA32(af[kk], bf, acc[c]);
    }
  }
}

// residual(bf16) + LayerNorm epilogue -> hb
__device__ __forceinline__ void ln_epilogue(f32x16 acc[4], size_t r0, int wrow0, int l31, int h5,
    const float* g, const float* b, u16* hb){
  float gc[4], bc[4];
  #pragma unroll
  for(int c=0;c<4;c++){ int col = c*32 + l31; gc[c]=g[col]; bc[c]=b[col]; }
  #pragma unroll
  for(int r=0;r<16;r++){
    int rowl = wrow0 + (r&3) + 8*(r>>2) + 4*h5;
    size_t base = (r0 + rowl)*(size_t)D;
    float v[4];
    #pragma unroll
    for(int c=0;c<4;c++) v[c] = acc[c][r] + b2f(hb[base + c*32 + l31]);
    float s = rsum32(v[0]+v[1]+v[2]+v[3]);
    float mean = s * (1.0f/128.0f);
    float dd[4]; float q = 0.f;
    #pragma unroll
    for(int c=0;c<4;c++){ dd[c]=v[c]-mean; q += dd[c]*dd[c]; }
    q = rsum32(q);
    float rs = rsqrtf(q*(1.0f/128.0f) + 1e-5f);
    #pragma unroll
    for(int c=0;c<4;c++){
      float o = dd[c]*rs*gc[c] + bc[c];
      hb[base + c*32 + l31] = f2b(o);
    }
  }
}

// ---------------- h0 -> hb (bf16) ----------------
__global__ __launch_bounds__(256) void k_hinit(const float* __restrict__ h0, u16* __restrict__ hb){
  int i = blockIdx.x*256 + threadIdx.x;
  float4 v = ((const float4*)h0)[i];
  ushort4 p; p.x=f2b(v.x); p.y=f2b(v.y); p.z=f2b(v.z); p.w=f2b(v.w);
  ((ushort4*)hb)[i] = p;
}

// ---------------- leaf embedding + LN ----------------
__global__ __launch_bounds__(256) void k_embed(const int* __restrict__ x, const int* __restrict__ pos,
    const int* __restrict__ leaf, const float* __restrict__ emb,
    const float* __restrict__ g, const float* __restrict__ b, u16* __restrict__ hb){
  int row = blockIdx.x*4 + (threadIdx.x>>6);
  int lane = threadIdx.x & 63;
  int tok = x[row]; float p = (float)pos[row];
  float v[2];
  #pragma unroll
  for(int j=0;j<2;j++){
    int d = lane + 64*j;
    float freq = expf(-0.07195578515529633f * (float)(d & ~1));
    float ang = p * freq;
    float pe = (d&1) ? cosf(ang) : sinf(ang);
    v[j] = emb[(size_t)tok*D + d] * 11.313708498984761f + pe;
  }
  float mean = wredsum(v[0]+v[1]) * (1.0f/128.0f);
  float d0 = v[0]-mean, d1 = v[1]-mean;
  float var = wredsum(d0*d0 + d1*d1) * (1.0f/128.0f);
  float rs = rsqrtf(var + 1e-5f);
  size_t orow = (size_t)leaf[row];
  hb[orow*D + lane]      = f2b(d0*rs*g[lane]    + b[lane]);
  hb[orow*D + lane + 64] = f2b(d1*rs*g[lane+64] + b[lane+64]);
}

// ---------------- weight transpose + bf16 convert ----------------
__global__ __launch_bounds__(256) void k_wconv(const float* __restrict__ Wq, const float* __restrict__ Wk,
    const float* __restrict__ Wv, const float* __restrict__ Wo,
    const float* __restrict__ W1, const float* __restrict__ W2,
    u16* __restrict__ wqt, u16* __restrict__ wkt, u16* __restrict__ wvt, u16* __restrict__ wot,
    u16* __restrict__ w1t, u16* __restrict__ w2t){
  int e = blockIdx.x*256 + threadIdx.x;     // NLAYER*196608 total
  int l = e / 196608, r = e % 196608;
  if(r < 65536){
    int w = r >> 14, i = r & 16383;
    int n = i >> 7, k = i & 127;
    const float* src = (w==0)?Wq:(w==1)?Wk:(w==2)?Wv:Wo;
    u16* dst = (w==0)?wqt:(w==1)?wkt:(w==2)?wvt:wot;
    dst[l*16384 + n*128 + k] = f2b(src[l*16384 + k*128 + n]);
  } else if(r < 131072){
    int i = r - 65536; int n = i >> 7, k = i & 127;      // n in 0..511
    w1t[l*65536 + n*128 + k] = f2b(W1[l*65536 + k*512 + n]);
  } else {
    int i = r - 131072; int n = i >> 9, f = i & 511;     // n in 0..127
    w2t[l*65536 + n*512 + f] = f2b(W2[l*65536 + f*128 + n]);
  }
}

// ---------------- CSR build ----------------
__global__ __launch_bounds__(256) void k_count(const int* __restrict__ dst, int* __restrict__ cnt){
  int e = blockIdx.x*256 + threadIdx.x;
  atomicAdd(&cnt[dst[e]], 1);
}
__global__ __launch_bounds__(256) void k_scan1(const int* __restrict__ cnt, int* __restrict__ part,
                                               int* __restrict__ bsum){
  __shared__ int s[256];
  int tid = threadIdx.x; int i = blockIdx.x*256 + tid;
  int v = cnt[i]; s[tid]=v; __syncthreads();
  for(int off=1; off<256; off<<=1){
    int t=(tid>=off)? s[tid-off]:0; __syncthreads();
    s[tid]+=t; __syncthreads();
  }
  part[i] = s[tid]-v;
  if(tid==255) bsum[blockIdx.x] = s[255];
}
__global__ __launch_bounds__(512) void k_scan2(int* __restrict__ bsum){
  __shared__ int s[512];
  int tid = threadIdx.x;
  int v = bsum[tid]; s[tid] = v; __syncthreads();
  for(int off=1; off<512; off<<=1){
    int t = (tid>=off)? s[tid-off]:0; __syncthreads();
    s[tid] += t; __syncthreads();
  }
  bsum[tid] = s[tid] - v;
}
__global__ __launch_bounds__(256) void k_scan3(const int* __restrict__ part, const int* __restrict__ bsum,
                                               int* __restrict__ indptr, int* __restrict__ cursor){
  int i = blockIdx.x*256 + threadIdx.x;
  int v = part[i] + bsum[i>>8];
  indptr[i] = v; cursor[i] = v;
  if(i==0) indptr[NN] = ETOT;
}
__global__ __launch_bounds__(256) void k_scatter(const int* __restrict__ src, const int* __restrict__ dst,
    int* __restrict__ cursor, int* __restrict__ esrc){
  int e = blockIdx.x*256 + threadIdx.x;
  int p = atomicAdd(&cursor[dst[e]], 1);
  esrc[p] = src[e];
}

// ---------------- QKV GEMM: one block does q,k,v; A-frags loaded once ---------------
__global__ __launch_bounds__(256,3) void k_qkv(const u16* __restrict__ hb,
    const u16* __restrict__ wqt, const u16* __restrict__ wkt, const u16* __restrict__ wvt,
    const float* __restrict__ bq, const float* __restrict__ bk, const float* __restrict__ bv,
    u16* __restrict__ qb, u16* __restrict__ kb, u16* __restrict__ vb){
  __shared__ u16 Bs[128*128];
  int tid = threadIdx.x;
  int lane = tid & 63, wv_ = tid >> 6;
  int l31 = lane & 31, h5 = lane >> 5, lkh = h5*16;
  int wrow0 = wv_*32;
  size_t r0 = (size_t)blockIdx.x * 128;

  stage_B(wqt, D, 0, Bs, wv_, lane);
  bf16x8 af[8];
  const u16* arow = hb + (r0 + wrow0 + l31)*(size_t)D + h5*8;
  #pragma unroll
  for(int kk=0;kk<8;kk++) af[kk] = *(const bf16x8*)(arow + kk*16);

  const u16* wt[3]    = {wqt,wkt,wvt};
  const float* bias[3] = {bq,bk,bv};
  u16* outp[3] = {qb,kb,vb};
  #pragma unroll
  for(int w=0; w<3; w++){
    if(w){
      __syncthreads();                 // prior mfma done reading Bs
      stage_B(wt[w], D, 0, Bs, wv_, lane);
    }
    f32x16 acc[4];
    #pragma unroll
    for(int c=0;c<4;c++){
      float bb = bias[w][c*32+l31];
      #pragma unroll
      for(int i=0;i<16;i++) acc[c][i] = bb;
    }
    __syncthreads();                   // staging complete
    mfma_regA(af, Bs, l31, lkh, acc);
    u16* op = outp[w];
    #pragma unroll
    for(int c=0;c<4;c++){
      int col = c*32 + l31;
      #pragma unroll
      for(int r=0;r<16;r++){
        int row = wrow0 + (r&3) + 8*(r>>2) + 4*h5;
        op[(r0+row)*(size_t)D + col] = f2b(acc[c][r]);
      }
    }
  }
}

// ------- attention: one wave/node; peeled first batch; MSB-first reduce-scatter ------
__global__ __launch_bounds__(256,6) void k_attn(const u16* qb, const u16* __restrict__ kb,
    const u16* __restrict__ vb, const int* __restrict__ indptr, const int* __restrict__ esrc,
    u16* aggb){
  int node = blockIdx.x*4 + (threadIdx.x>>6);
  int lane = threadIdx.x & 63;
  int hd = lane >> 3, eslot = lane & 7;
  int beg = indptr[node], end = indptr[node+1];
  float qr[16];
  {
    const uint4* qp = (const uint4*)(qb + (size_t)node*D + hd*16);
    uint4 a = qp[0], b = qp[1];
    u32 w[8] = {a.x,a.y,a.z,a.w,b.x,b.y,b.z,b.w};
    #pragma unroll
    for(int i=0;i<8;i++){ qr[2*i] = blo(w[i]); qr[2*i+1] = bhi(w[i]); }
  }
  float m = -3.0e38f, den = 0.f;
  float acc[16];
  #pragma unroll
  for(int i=0;i<16;i++) acc[i] = 0.f;

  // ---- peeled first batch: m=p, den=1, acc=v exactly (exp(0)=1) ----
  {
    int e = beg + eslot;
    if(e < end){
      int s = esrc[e];
      const uint4* kp = (const uint4*)(kb + (size_t)s*D + hd*16);
      uint4 k0 = kp[0], k1 = kp[1];
      const uint4* vp = (const uint4*)(vb + (size_t)s*D + hd*16);
      uint4 v0 = vp[0], v1 = vp[1];
      u32 kw[8] = {k0.x,k0.y,k0.z,k0.w,k1.x,k1.y,k1.z,k1.w};
      float p = 0.f, p2 = 0.f;
      #pragma unroll
      for(int i=0;i<8;i++){ p = fmaf(blo(kw[i]), qr[2*i], p); p2 = fmaf(bhi(kw[i]), qr[2*i+1], p2); }
      m = (p + p2)*0.25f;
      den = 1.f;
      u32 vw[8] = {v0.x,v0.y,v0.z,v0.w,v1.x,v1.y,v1.z,v1.w};
      #pragma unroll
      for(int i=0;i<8;i++){ acc[2*i] = blo(vw[i]); acc[2*i+1] = bhi(vw[i]); }
    }
  }
  // ---- remaining batches: full online-softmax update ----
  for(int e0=beg+8; e0<end; e0+=8){
    int e = e0 + eslot;
    if(e < end){
      int s = esrc[e];
      const uint4* kp = (const uint4*)(kb + (size_t)s*D + hd*16);
      uint4 k0 = kp[0], k1 = kp[1];
      const uint4* vp = (const uint4*)(vb + (size_t)s*D + hd*16);
      uint4 v0 = vp[0], v1 = vp[1];
      u32 kw[8] = {k0.x,k0.y,k0.z,k0.w,k1.x,k1.y,k1.z,k1.w};
      float p = 0.f, p2 = 0.f;
      #pragma unroll
      for(int i=0;i<8;i++){ p = fmaf(blo(kw[i]), qr[2*i], p); p2 = fmaf(bhi(kw[i]), qr[2*i+1], p2); }
      p = (p + p2)*0.25f;                       // 1/sqrt(DK)
      float nm = fmaxf(m, p);
      float fs = __expf(m - nm);
      float w  = __expf(p - nm);
      den = den*fs + w;
      u32 vw[8] = {v0.x,v0.y,v0.z,v0.w,v1.x,v1.y,v1.z,v1.w};
      #pragma unroll
      for(int i=0;i<8;i++){
        acc[2*i]   = fmaf(acc[2*i],   fs, w*blo(vw[i]));
        acc[2*i+1] = fmaf(acc[2*i+1], fs, w*bhi(vw[i]));
      }
      m = nm;
    }
  }
  // merge (m, den) across 8 slots
  float mo = m;
  #pragma unroll
  for(int s=1; s<8; s<<=1){
    float m2 = __shfl_xor(m, s); float d2 = __shfl_xor(den, s);
    float nm = fmaxf(m, m2);
    den = den*__expf(m-nm) + d2*__expf(m2-nm);
    m = nm;
  }
  // rescale local partials, then MSB-first reduce-scatter (lane ends owning dims 2*eslot)
  float sc = __expf(mo - m);
  #pragma unroll
  for(int i=0;i<16;i++) acc[i] *= sc;
  #pragma unroll
  for(int lvl=0; lvl<3; lvl++){
    const int half = 8 >> lvl;          // 8,4,2
    const int msk = 4 >> lvl;           // 4,2,1  (MSB first!)
    bool hi = (eslot & msk) != 0;
    #pragma unroll
    for(int i=0;i<half;i++){
      float a = acc[i], b = acc[i+half];
      acc[i]      = hi ? b : a;
      acc[i+half] = hi ? a : b;
    }
    #pragma unroll
    for(int i=0;i<half;i++) acc[i] += __shfl_xor(acc[i+half], msk);
  }
  // lane owns dims (2*eslot, 2*eslot+1): store byte offset = lane*4 -> fully coalesced
  float rin = 1.0f/den;
  u32 pk = (u32)f2b(acc[0]*rin) | ((u32)f2b(acc[1]*rin)<<16);
  *(u32*)(aggb + (size_t)node*D + hd*16 + eslot*2) = pk;
}

// ---------------- O-proj + residual + LN1 ----------------
__global__ __launch_bounds__(256,3) void k_owo(const u16* __restrict__ aggb, const u16* __restrict__ wot,
    const float* __restrict__ bo, const float* __restrict__ g1, const float* __restrict__ b1,
    u16* hb){
  __shared__ u16 Bs[128*128];
  int tid = threadIdx.x;
  int lane = tid & 63, wv_ = tid >> 6;
  int l31 = lane & 31, h5 = lane >> 5, lkh = h5*16;
  int wrow0 = wv_*32;
  size_t r0 = (size_t)blockIdx.x * 128;
  stage_B(wot, D, 0, Bs, wv_, lane);
  bf16x8 af[8];
  const u16* arow = aggb + (r0 + wrow0 + l31)*(size_t)D + h5*8;
  #pragma unroll
  for(int kk=0;kk<8;kk++) af[kk] = *(const bf16x8*)(arow + kk*16);
  f32x16 acc[4];
  #pragma unroll
  for(int c=0;c<4;c++){
    float bb = bo[c*32+l31];
    #pragma unroll
    for(int i=0;i<16;i++) acc[c][i] = bb;
  }
  __syncthreads();
  mfma_regA(af, Bs, l31, lkh, acc);
  ln_epilogue(acc, r0, wrow0, l31, h5, g1, b1, hb);
}

// ---------------- FFN: in-register transpose between the two GEMMs -------------------
__global__ __launch_bounds__(256,2) void k_ffn(const u16* __restrict__ w1t, const u16* __restrict__ w2t,
    const float* __restrict__ b1, const float* __restrict__ b2,
    const float* __restrict__ g2, const float* __restrict__ bb2,
    u16* hb){
  __shared__ u16 B1s[128*128];
  __shared__ u16 B2s[128*128];
  int tid = threadIdx.x;
  int lane = tid & 63, wv_ = tid >> 6;
  int l31 = lane & 31, h5 = lane >> 5, lkh = h5*16;
  int wrow0 = wv_*32;
  size_t r0 = (size_t)blockIdx.x * 128;
  bf16x8 af[8];
  const u16* arow = hb + (r0 + wrow0 + l31)*(size_t)D + h5*8;
  #pragma unroll
  for(int kk=0;kk<8;kk++) af[kk] = *(const bf16x8*)(arow + kk*16);
  f32x16 out[4];
  #pragma unroll
  for(int c=0;c<4;c++){
    float bb = b2[c*32+l31];
    #pragma unroll
    for(int i=0;i<16;i++) out[c][i] = bb;
  }
  for(int ch=0; ch<4; ch++){
    if(ch) __syncthreads();
    stage_B(w1t + ch*128*D, D, 0, B1s, wv_, lane);
    stage_B(w2t, DFF, ch*128, B2s, wv_, lane);
    __syncthreads();
    // stage1: acc2[c] = (W1 chunk)(A: rows f) x (af)(B: cols = wave's 32 nodes) = T^T
    f32x16 acc2[4];
    #pragma unroll
    for(int c=0;c<4;c++){
      #pragma unroll
      for(int r=0;r<16;r++){
        int foff = (r&3) + 8*(r>>2) + 4*h5;
        acc2[c][r] = b1[ch*128 + c*32 + foff];
      }
    }
    #pragma unroll
    for(int kk=0;kk<8;kk++){
      #pragma unroll
      for(int c=0;c<4;c++){
        bf16x8 w1f = ldfrag(B1s, c*32 + l31, kk*32 + lkh);
        acc2[c] = MFMA32(w1f, af[kk], acc2[c]);
      }
    }
    // relu + pack bf16 + h5 half-exchange -> A-fragments for stage2
    bf16x8 af2[8];
    bool hb5 = (h5 != 0);
    #pragma unroll
    for(int c=0;c<4;c++){
      u32 pk[8];
      #pragma unroll
      for(int t=0;t<8;t++){
        float lo  = fmaxf(acc2[c][2*t],   0.f);
        float hi2 = fmaxf(acc2[c][2*t+1], 0.f);
        u32 r_;
        asm("v_cvt_pk_bf16_f32 %0, %1, %2" : "=v"(r_) : "v"(lo), "v"(hi2));
        pk[t] = r_;
      }
      // h5=0 holds f-offsets {0,2,8,10,16,18,24,26}; h5=1 holds {4,6,12,14,20,22,28,30}
      u32 s0 = hb5 ? pk[0] : pk[2];
      u32 s1 = hb5 ? pk[1] : pk[3];
      u32 s2 = hb5 ? pk[4] : pk[6];
      u32 s3 = hb5 ? pk[5] : pk[7];
      u32 g0 = (u32)__shfl_xor((int)s0, 32);
      u32 g1 = (u32)__shfl_xor((int)s1, 32);
      u32 g2_ = (u32)__shfl_xor((int)s2, 32);
      u32 g3 = (u32)__shfl_xor((int)s3, 32);
      u32x4 A0 = { hb5 ? g0 : pk[0], hb5 ? g1 : pk[1], hb5 ? pk[2] : g0, hb5 ? pk[3] : g1 };
      u32x4 A1 = { hb5 ? g2_ : pk[4], hb5 ? g3 : pk[5], hb5 ? pk[6] : g2_, hb5 ? pk[7] : g3 };
      af2[2*c]   = __builtin_bit_cast(bf16x8, A0);
      af2[2*c+1] = __builtin_bit_cast(bf16x8, A1);
    }
    // stage2: out += T(A: rows = wave's nodes) x (W2 chunk)(B: cols n)
    #pragma unroll
    for(int kk=0;kk<8;kk++){
      #pragma unroll
      for(int c=0;c<4;c++){
        bf16x8 w2f = ldfrag(B2s, c*32 + l31, kk*32 + lkh);
        out[c] = MFMA32(af2[kk], w2f, out[c]);
      }
    }
  }
  ln_epilogue(out, r0, wrow0, l31, h5, g2, bb2, hb);
}

// ---------------- readout ----------------
__global__ __launch_bounds__(64) void k_readout(const u16* __restrict__ hb, const int* __restrict__ rid,
    const float* __restrict__ gw, const float* __restrict__ gb, float* __restrict__ out){
  int r = blockIdx.x; int lane = threadIdx.x;
  size_t node = (size_t)rid[r];
  float h0v = b2f(hb[node*D + lane]), h1v = b2f(hb[node*D + 64 + lane]);
  float lg[NCLS];
  #pragma unroll
  for(int c=0;c<NCLS;c++){
    float p = h0v*gw[lane*NCLS + c] + h1v*gw[(lane+64)*NCLS + c];
    lg[c] = wredsum(p) + gb[c];
  }
  float mx = lg[0];
  #pragma unroll
  for(int c=1;c<NCLS;c++) mx = fmaxf(mx, lg[c]);
  float se = 0.f;
  #pragma unroll
  for(int c=0;c<NCLS;c++) se += expf(lg[c]-mx);
  float lse = mx + logf(se);
  if(lane < NCLS) out[(size_t)r*NCLS + lane] = lg[lane] - lse;
}

extern "C" void kernel_launch(void* const* d_in, const int* in_sizes, int n_in,
                              void* d_out, int out_size, void* d_ws, size_t ws_size,
                              hipStream_t stream) {
  const int* x    = (const int*)d_in[0];
  const int* pos  = (const int*)d_in[1];
  const int* leaf = (const int*)d_in[2];
  const int* src  = (const int*)d_in[3];
  const int* dst  = (const int*)d_in[4];
  const int* rid  = (const int*)d_in[5];
  const float* h0 = (const float*)d_in[6];
  const float* emb= (const float*)d_in[7];
  const float* eng= (const float*)d_in[8];
  const float* enb= (const float*)d_in[9];
  const float* Wq = (const float*)d_in[10];
  const float* bq = (const float*)d_in[11];
  const float* Wk = (const float*)d_in[12];
  const float* bk = (const float*)d_in[13];
  const float* Wv = (const float*)d_in[14];
  const float* bv = (const float*)d_in[15];
  const float* Wo = (const float*)d_in[16];
  const float* bo = (const float*)d_in[17];
  const float* l1g= (const float*)d_in[18];
  const float* l1b= (const float*)d_in[19];
  const float* W1 = (const float*)d_in[20];
  const float* b1 = (const float*)d_in[21];
  const float* W2 = (const float*)d_in[22];
  const float* b2 = (const float*)d_in[23];
  const float* l2g= (const float*)d_in[24];
  const float* l2b= (const float*)d_in[25];
  const float* gw = (const float*)d_in[26];
  const float* gb = (const float*)d_in[27];
  float* out = (float*)d_out;

  char* ws = (char*)d_ws;
  u16* hb     = (u16*)(ws);                          // 33,554,432
  u16* qb     = (u16*)(ws + 33554432);               // 33,554,432 (agg aliases)
  u16* kb     = (u16*)(ws + 67108864);               // 33,554,432
  u16* vb     = (u16*)(ws + 100663296);              // 33,554,432
  u16* wqt    = (u16*)(ws + 134217728);              // 131,072
  u16* wkt    = (u16*)(ws + 134348800);
  u16* wvt    = (u16*)(ws + 134479872);
  u16* wot    = (u16*)(ws + 134610944);
  u16* w1t    = (u16*)(ws + 134742016);              // 524,288
  u16* w2t    = (u16*)(ws + 135266304);              // 524,288
  int* indptr = (int*)(ws + 135790592);              // 524,544
  int* cursor = (int*)(ws + 136315136);              // 524,288
  int* part   = (int*)(ws + 136839424);              // 524,288
  int* bsum   = (int*)(ws + 137363712);              // 2,048
  int* esrc   = (int*)(ws + 137365760);              // 2,621,440  -> ~140 MB total

  k_hinit<<<NN*D/4/256, 256, 0, stream>>>(h0, hb);
  k_embed<<<NLEAF/4, 256, 0, stream>>>(x, pos, leaf, emb, eng, enb, hb);
  k_wconv<<<NLAYER*196608/256, 256, 0, stream>>>(Wq,Wk,Wv,Wo,W1,W2, wqt,wkt,wvt,wot,w1t,w2t);

  hipMemsetAsync(cursor, 0, NN*sizeof(int), stream);
  k_count  <<<ETOT/256, 256, 0, stream>>>(dst, cursor);
  k_scan1  <<<NN/256, 256, 0, stream>>>(cursor, part, bsum);
  k_scan2  <<<1, 512, 0, stream>>>(bsum);
  k_scan3  <<<NN/256, 256, 0, stream>>>(part, bsum, indptr, cursor);
  k_scatter<<<ETOT/256, 256, 0, stream>>>(src, dst, cursor, esrc);

  for(int l=0; l<NLAYER; l++){
    k_qkv<<<NN/128, 256, 0, stream>>>(hb, wqt + l*16384, wkt + l*16384, wvt + l*16384,
                                      bq + l*D, bk + l*D, bv + l*D, qb, kb, vb);
    k_attn<<<NN/4, 256, 0, stream>>>(qb, kb, vb, indptr, esrc, qb);
    k_owo<<<NN/128, 256, 0, stream>>>(qb, wot + l*16384, bo + l*D,
                                      l1g + l*D, l1b + l*D, hb);
    k_ffn<<<NN/128, 256, 0, stream>>>(w1t + l*65536, w2t + l*65536,
                                      b1 + l*DFF, b2 + l*D, l2g + l*D, l2b + l*D, hb);
  }
  k_readout<<<NREAD, 64, 0, stream>>>(hb, rid, gw, gb, out);
}